// Round 3
// baseline (363.596 us; speedup 1.0000x reference)
//
#include <hip/hip_runtime.h>
#include <hip/hip_bf16.h>

#define NB 4
#define NI 40000
#define DI 512
#define NH 128
#define TM 32
#define NT 1250         // tiles per batch (1250*32 = 40000)
#define SUBB 128        // sub-blocks per batch (grid = 4*128)

typedef __attribute__((ext_vector_type(8))) short bf16x8;
typedef __attribute__((ext_vector_type(4))) float f32x4;

__device__ __forceinline__ ushort f2b(float f) {
    union { float f; unsigned u; } x; x.f = f;
    unsigned r = x.u + 0x7FFFu + ((x.u >> 16) & 1u);
    return (ushort)(r >> 16);
}
__device__ __forceinline__ float b2f(ushort u) {
    union { unsigned u; float f; } x; x.u = ((unsigned)u) << 16;
    return x.f;
}
__device__ __forceinline__ float tanh_fast(float x) {
    x = fminf(15.f, fmaxf(-15.f, x));
    float e = __expf(2.f * x);
    return (e - 1.f) / (e + 1.f);
}

// ---------------- weight transpose + bf16 convert ----------------
__global__ void k_wt(const float* __restrict__ w1, const float* __restrict__ w2,
                     ushort* __restrict__ w1t, ushort* __restrict__ w2t) {
    int idx = blockIdx.x * 256 + threadIdx.x;
    if (idx < 65536) {
        int j = idx >> 9, i = idx & 511;
        w1t[idx] = f2b(w1[i * 128 + j]);
    } else if (idx < 81920) {
        int r = idx - 65536;
        int j = r >> 7, k = r & 127;
        w2t[r] = f2b(w2[k * 128 + j]);
    }
}

// ---------------- argmax stage 1 ----------------
__global__ void k_am1(const float* __restrict__ c, float* __restrict__ pv, int* __restrict__ pi) {
    int blk = blockIdx.x;
    int bo = blk >> 4, ch = blk & 15;
    int b = bo >> 1, o = bo & 1;
    __shared__ float rv[256];
    __shared__ int   ri[256];
    int tid = threadIdx.x;
    float bv = -3.402823466e38f; int bi = 0x7fffffff;
    for (int n = ch * 2500 + tid; n < (ch + 1) * 2500; n += 256) {
        float v = c[((size_t)b * NI + n) * 2 + o];
        if (v > bv || (v == bv && n < bi)) { bv = v; bi = n; }
    }
    rv[tid] = bv; ri[tid] = bi;
    __syncthreads();
    for (int s = 128; s > 0; s >>= 1) {
        if (tid < s) {
            if (rv[tid + s] > rv[tid] || (rv[tid + s] == rv[tid] && ri[tid + s] < ri[tid])) {
                rv[tid] = rv[tid + s]; ri[tid] = ri[tid + s];
            }
        }
        __syncthreads();
    }
    if (tid == 0) { pv[blk] = rv[0]; pi[blk] = ri[0]; }
}

// ---------------- argmax stage 2 ----------------
__global__ void k_am2(const float* __restrict__ pv, const int* __restrict__ pi,
                      int* __restrict__ topidx) {
    int bo = blockIdx.x;
    if (threadIdx.x == 0) {
        float bv = -3.402823466e38f; int bi = 0x7fffffff;
        for (int ch = 0; ch < 16; ++ch) {
            float v = pv[bo * 16 + ch]; int idx = pi[bo * 16 + ch];
            if (v > bv || (v == bv && idx < bi)) { bv = v; bi = idx; }
        }
        topidx[bo] = bi;
    }
}

// ---------------- q_max MLP ----------------
__global__ void k_qmax(const float* __restrict__ feats, const int* __restrict__ topidx,
                       const float* __restrict__ w1, const float* __restrict__ b1,
                       const float* __restrict__ w2, const float* __restrict__ b2,
                       float* __restrict__ qmax) {
    int bo = blockIdx.x;
    int b = bo >> 1;
    __shared__ float xs[DI];
    __shared__ float hs[NH];
    int tid = threadIdx.x;               // 512
    const float* x = feats + ((size_t)b * NI + topidx[bo]) * DI;
    if (tid < DI) xs[tid] = x[tid];
    __syncthreads();
    int j = tid >> 2, part = tid & 3;
    float p = 0.f;
    for (int i = part * 128; i < part * 128 + 128; ++i)
        p += xs[i] * w1[i * NH + j];
    p += __shfl_xor(p, 1); p += __shfl_xor(p, 2);
    if (part == 0) { float h = p + b1[j]; hs[j] = h > 0.f ? h : 0.f; }
    __syncthreads();
    p = 0.f;
    for (int i = part * 32; i < part * 32 + 32; ++i)
        p += hs[i] * w2[i * NH + j];
    p += __shfl_xor(p, 1); p += __shfl_xor(p, 2);
    if (part == 0) qmax[bo * NH + j] = tanhf(p + b2[j]);
}

// ---------------- main fused kernel (persistent, double-buffered) ----------------
#define L1G(C0, C1, N0, N1, G)                                                  \
  {                                                                             \
    if ((G) < 3) {                                                              \
      _Pragma("unroll")                                                         \
      for (int j = 0; j < 4; ++j) {                                             \
        N0[j] = *(const bf16x8*)(wb0 + ((G) + 1) * 128 + j * 32);               \
        N1[j] = *(const bf16x8*)(wb1 + ((G) + 1) * 128 + j * 32);               \
      }                                                                         \
    }                                                                           \
    _Pragma("unroll")                                                           \
    for (int j = 0; j < 4; ++j) {                                               \
      int kb = (((G) * 4 + j) * 32 + lk) * 2;                                   \
      bf16x8 a0 = *(const bf16x8*)(xrow0 + (kb ^ xsw));                         \
      bf16x8 a1 = *(const bf16x8*)(xrow1 + (kb ^ xsw));                         \
      acc00 = __builtin_amdgcn_mfma_f32_16x16x32_bf16(a0, C0[j], acc00, 0, 0, 0);\
      acc01 = __builtin_amdgcn_mfma_f32_16x16x32_bf16(a0, C1[j], acc01, 0, 0, 0);\
      acc10 = __builtin_amdgcn_mfma_f32_16x16x32_bf16(a1, C0[j], acc10, 0, 0, 0);\
      acc11 = __builtin_amdgcn_mfma_f32_16x16x32_bf16(a1, C1[j], acc11, 0, 0, 0);\
    }                                                                           \
  }

#define EPI1(ACC, M, N, BIAS)                                                   \
  _Pragma("unroll")                                                             \
  for (int r = 0; r < 4; ++r) {                                                 \
    int row = (M) * 16 + l4 + r;                                                \
    float v = ACC[r] + (BIAS);                                                  \
    *(ushort*)((char*)h_lds + row * 256 +                                       \
               (((wn * 32 + (N) * 16 + lr) * 2) ^ ((row & 7) << 4))) =          \
        f2b(v > 0.f ? v : 0.f);                                                 \
  }

__global__ __launch_bounds__(256, 2)
void k_main(const float* __restrict__ feats,
            const ushort* __restrict__ w1t, const ushort* __restrict__ w2t,
            const float* __restrict__ b1, const float* __restrict__ b2,
            const float* __restrict__ qmax,
            float* __restrict__ s_ws, float* __restrict__ zp, float* __restrict__ Up) {
    __shared__ ushort x_lds[2 * TM * 512];   // 64 KB, 2 buffers, XOR-swizzled
    __shared__ ushort h_lds[TM * 128];       // 8 KB, XOR-swizzled
    __shared__ float  sp_lds[4][TM][2];      // 1 KB
    __shared__ float  e_lds[TM * 2];

    const int tid = threadIdx.x;
    const int sub = blockIdx.x & (SUBB - 1);
    const int b   = blockIdx.x >> 7;

    const int wn = tid >> 6;
    const int lane = tid & 63;
    const int lr = lane & 15;
    const int lk = (lane >> 4) * 8;
    const int l4 = (lane >> 4) * 4;
    const int xsw = (lr & 7) << 4;

    // per-thread constants
    const int col0 = wn * 32 + lr;
    const int col1 = col0 + 16;
    const float rb1_0 = b1[col0], rb1_1 = b1[col1];
    const float rb2_0 = b2[col0], rb2_1 = b2[col1];
    const float qm00 = qmax[b * 256 + col0];        // o=0, n=0
    const float qm01 = qmax[b * 256 + col1];        // o=0, n=1
    const float qm10 = qmax[b * 256 + NH + col0];   // o=1, n=0
    const float qm11 = qmax[b * 256 + NH + col1];   // o=1, n=1

    // W2 fragments in registers (reused across all tiles)
    bf16x8 W2f0[4], W2f1[4];
#pragma unroll
    for (int ks = 0; ks < 4; ++ks) {
        W2f0[ks] = *(const bf16x8*)&w2t[(size_t)col0 * NH + ks * 32 + lk];
        W2f1[ks] = *(const bf16x8*)&w2t[(size_t)col1 * NH + ks * 32 + lk];
    }

    const ushort* wb0 = w1t + (size_t)(wn * 32 + lr) * DI + lk;
    const ushort* wb1 = wb0 + (size_t)16 * DI;

    // persistent accumulators
    float u00 = 0.f, u01 = 0.f, u10 = 0.f, u11 = 0.f;
    float zacc = 0.f;

    float4 pf[16];

    // ---- prologue: stage first tile into buffer 0 ----
    {
        const float4* xg4 = (const float4*)(feats + ((size_t)b * NI + sub * TM) * DI);
#pragma unroll
        for (int q = 0; q < 16; ++q) pf[q] = xg4[tid + q * 256];
#pragma unroll
        for (int q = 0; q < 16; ++q) {
            int idx = tid + q * 256;
            int row = idx >> 7, c4 = idx & 127;
            unsigned lo, hi;
            asm("v_cvt_pk_bf16_f32 %0, %1, %2" : "=v"(lo) : "v"(pf[q].x), "v"(pf[q].y));
            asm("v_cvt_pk_bf16_f32 %0, %1, %2" : "=v"(hi) : "v"(pf[q].z), "v"(pf[q].w));
            uint2 u; u.x = lo; u.y = hi;
            *(uint2*)((char*)x_lds + row * 1024 + ((c4 * 8) ^ ((row & 7) << 4))) = u;
        }
    }
    __syncthreads();

    int cur = 0;
    for (int t = sub; t < NT; t += SUBB) {
        const int nxt = cur ^ 1;
        const bool more = (t + SUBB < NT);

        // issue prefetch loads for next tile (stay in flight through compute)
        if (more) {
            const float4* xg4 = (const float4*)(feats + ((size_t)b * NI + (t + SUBB) * TM) * DI);
#pragma unroll
            for (int q = 0; q < 16; ++q) pf[q] = xg4[tid + q * 256];
        }

        const char* xrow0 = (const char*)x_lds + cur * 32768 + lr * 1024;
        const char* xrow1 = (const char*)x_lds + cur * 32768 + (16 + lr) * 1024;

        // ---- layer 1: X[32,512] @ W1[512,128], B pipelined from L2 ----
        f32x4 acc00 = {}, acc01 = {}, acc10 = {}, acc11 = {};
        bf16x8 BA0[4], BA1[4], BB0[4], BB1[4];
#pragma unroll
        for (int j = 0; j < 4; ++j) {
            BA0[j] = *(const bf16x8*)(wb0 + j * 32);
            BA1[j] = *(const bf16x8*)(wb1 + j * 32);
        }
        L1G(BA0, BA1, BB0, BB1, 0)
        L1G(BB0, BB1, BA0, BA1, 1)
        L1G(BA0, BA1, BB0, BB1, 2)
        L1G(BB0, BB1, BA0, BA1, 3)

        // ---- epilogue 1: bias + relu -> h_lds ----
        EPI1(acc00, 0, 0, rb1_0)
        EPI1(acc01, 0, 1, rb1_1)
        EPI1(acc10, 1, 0, rb1_0)
        EPI1(acc11, 1, 1, rb1_1)
        __syncthreads();

        // ---- layer 2: H[32,128] @ W2 (registers) ----
        f32x4 c200 = {}, c201 = {}, c210 = {}, c211 = {};
#pragma unroll
        for (int ks = 0; ks < 4; ++ks) {
            int kb = (ks * 32 + lk) * 2;
            bf16x8 a0 = *(const bf16x8*)((const char*)h_lds + lr * 256 + (kb ^ xsw));
            bf16x8 a1 = *(const bf16x8*)((const char*)h_lds + (16 + lr) * 256 + (kb ^ xsw));
            c200 = __builtin_amdgcn_mfma_f32_16x16x32_bf16(a0, W2f0[ks], c200, 0, 0, 0);
            c201 = __builtin_amdgcn_mfma_f32_16x16x32_bf16(a0, W2f1[ks], c201, 0, 0, 0);
            c210 = __builtin_amdgcn_mfma_f32_16x16x32_bf16(a1, W2f0[ks], c210, 0, 0, 0);
            c211 = __builtin_amdgcn_mfma_f32_16x16x32_bf16(a1, W2f1[ks], c211, 0, 0, 0);
        }

        // ---- epilogue 2: tanh + dot(qmax) + reduce over 128 cols ----
#pragma unroll
        for (int m = 0; m < 2; ++m)
#pragma unroll
            for (int r = 0; r < 4; ++r) {
                float q0 = tanh_fast((m ? c210[r] : c200[r]) + rb2_0);
                float q1 = tanh_fast((m ? c211[r] : c201[r]) + rb2_1);
                float p0 = q0 * qm00 + q1 * qm01;
                float p1 = q0 * qm10 + q1 * qm11;
                p0 += __shfl_xor(p0, 1); p1 += __shfl_xor(p1, 1);
                p0 += __shfl_xor(p0, 2); p1 += __shfl_xor(p1, 2);
                p0 += __shfl_xor(p0, 4); p1 += __shfl_xor(p1, 4);
                p0 += __shfl_xor(p0, 8); p1 += __shfl_xor(p1, 8);
                if (lr == 0) {
                    int row = m * 16 + l4 + r;
                    sp_lds[wn][row][0] = p0;
                    sp_lds[wn][row][1] = p1;
                }
            }
        __syncthreads();

        // ---- s-finish (wave 0) ----
        if (tid < 64) {
            int row = tid >> 1, o = tid & 1;
            float s = (sp_lds[0][row][o] + sp_lds[1][row][o] +
                       sp_lds[2][row][o] + sp_lds[3][row][o]) * 0.005f;
            s_ws[((size_t)(b * NI + t * TM + row)) * 2 + o] = s;
            float e = __expf(s);
            e_lds[row * 2 + o] = e;
            float z = e;
            z += __shfl_xor(z, 2);  z += __shfl_xor(z, 4);
            z += __shfl_xor(z, 8);  z += __shfl_xor(z, 16);
            z += __shfl_xor(z, 32);
            if (tid < 2) zacc += z;
        }

        // ---- write next tile into other buffer (waits on prefetch loads) ----
        if (more) {
#pragma unroll
            for (int q = 0; q < 16; ++q) {
                int idx = tid + q * 256;
                int row = idx >> 7, c4 = idx & 127;
                unsigned lo, hi;
                asm("v_cvt_pk_bf16_f32 %0, %1, %2" : "=v"(lo) : "v"(pf[q].x), "v"(pf[q].y));
                asm("v_cvt_pk_bf16_f32 %0, %1, %2" : "=v"(hi) : "v"(pf[q].z), "v"(pf[q].w));
                uint2 u; u.x = lo; u.y = hi;
                *(uint2*)((char*)x_lds + nxt * 32768 + row * 1024 + ((c4 * 8) ^ ((row & 7) << 4))) = u;
            }
        }
        __syncthreads();   // e_lds ready + nxt staged

        // ---- U phase: accumulate e-weighted X into registers ----
        {
            int bc = tid * 4;
#pragma unroll 8
            for (int n = 0; n < TM; ++n) {
                unsigned v = *(const unsigned*)((const char*)x_lds + cur * 32768 +
                                                n * 1024 + (bc ^ ((n & 7) << 4)));
                float x0 = b2f((ushort)(v & 0xffff));
                float x1 = b2f((ushort)(v >> 16));
                float e0 = e_lds[n * 2], e1 = e_lds[n * 2 + 1];
                u00 += e0 * x0; u01 += e0 * x1;
                u10 += e1 * x0; u11 += e1 * x1;
            }
        }
        __syncthreads();   // protect cur buffer before it is overwritten
        cur = nxt;
    }

    // ---- block epilogue: write U and z partials ----
    {
        size_t base = ((size_t)(b * SUBB + sub) * 2) * DI;
        float2 v0; v0.x = u00; v0.y = u01;
        float2 v1; v1.x = u10; v1.y = u11;
        *(float2*)&Up[base + tid * 2] = v0;
        *(float2*)&Up[base + DI + tid * 2] = v1;
        if (tid < 2) zp[(b * SUBB + sub) * 2 + tid] = zacc;
    }
}

// ---------------- Z reduce (128 partials per (b,o)) ----------------
__global__ void k_zred(const float* __restrict__ zp, float* __restrict__ Zt) {
    int bo = blockIdx.x; int b = bo >> 1, o = bo & 1;
    int tid = threadIdx.x;   // 64
    float z = zp[((b * SUBB + tid) * 2) + o] + zp[((b * SUBB + tid + 64) * 2) + o];
    z += __shfl_xor(z, 1);  z += __shfl_xor(z, 2);
    z += __shfl_xor(z, 4);  z += __shfl_xor(z, 8);
    z += __shfl_xor(z, 16); z += __shfl_xor(z, 32);
    if (tid == 0) Zt[bo] = z;
}

// ---------------- A output ----------------
__global__ void k_A(const float* __restrict__ s_ws, const float* __restrict__ Zt,
                    float* __restrict__ outA) {
    int idx = blockIdx.x * 256 + threadIdx.x;
    int b = idx / (NI * 2);
    int o = idx & 1;
    outA[idx] = __expf(s_ws[idx]) / Zt[b * 2 + o];
}

// ---------------- B output (sum 128 partials) ----------------
__global__ void k_B(const float* __restrict__ Up, const float* __restrict__ Zt,
                    float* __restrict__ outB) {
    int bo = blockIdx.x; int d = threadIdx.x;   // 512
    int b = bo >> 1, o = bo & 1;
    float u = 0.f;
    for (int s2 = 0; s2 < SUBB; ++s2)
        u += Up[(((size_t)(b * SUBB + s2)) * 2 + o) * DI + d];
    outB[bo * DI + d] = u / Zt[bo];
}

// ---------------- C output ----------------
__global__ void k_C(const float* __restrict__ outB, const float* __restrict__ fcc_w,
                    const float* __restrict__ fcc_b, float* __restrict__ outC) {
    int bo = blockIdx.x; int b = bo >> 1, o = bo & 1;
    __shared__ float red[256];
    int tid = threadIdx.x;
    float acc = 0.f;
    for (int idx = tid; idx < 2 * DI; idx += 256) {
        int i = idx >> 9, d = idx & 511;
        acc += outB[(b * 2 + i) * DI + d] * fcc_w[o * (2 * DI) + i * DI + d];
    }
    red[tid] = acc; __syncthreads();
    for (int s = 128; s > 0; s >>= 1) {
        if (tid < s) red[tid] += red[tid + s];
        __syncthreads();
    }
    if (tid == 0) outC[bo] = red[0] + fcc_b[o];
}

extern "C" void kernel_launch(void* const* d_in, const int* in_sizes, int n_in,
                              void* d_out, int out_size, void* d_ws, size_t ws_size,
                              hipStream_t stream) {
    const float* feats = (const float*)d_in[0];
    const float* c     = (const float*)d_in[1];
    const float* q_w1  = (const float*)d_in[2];
    const float* q_b1  = (const float*)d_in[3];
    const float* q_w2  = (const float*)d_in[4];
    const float* q_b2  = (const float*)d_in[5];
    const float* fcc_w = (const float*)d_in[6];
    const float* fcc_b = (const float*)d_in[7];
    float* out = (float*)d_out;

    // workspace layout (bytes)
    char* w = (char*)d_ws;
    ushort* w1t  = (ushort*)(w);                 // 131072
    ushort* w2t  = (ushort*)(w + 131072);        // 32768   -> 163840
    float* qmaxb = (float*)(w + 163840);         // 4096    -> 167936
    int*   topi  = (int*)(w + 167936);           // 32      -> 167968
    float* Zt    = (float*)(w + 167968);         // 32      -> 168000
    float* pv    = (float*)(w + 168000);         // 512     -> 168512
    int*   pi    = (int*)(w + 168512);           // 512     -> 169024
    float* s_ws  = (float*)(w + 169024);         // 1280000 -> 1449024
    float* zp    = (float*)(w + 1449024);        // 4096    -> 1453120
    float* Up    = (float*)(w + 1453120);        // 2097152 -> 3550272

    float* outC = out;
    float* outA = out + 8;
    float* outB = out + 8 + NB * NI * 2;

    k_wt<<<320, 256, 0, stream>>>(q_w1, q_w2, w1t, w2t);
    k_am1<<<128, 256, 0, stream>>>(c, pv, pi);
    k_am2<<<8, 64, 0, stream>>>(pv, pi, topi);
    k_qmax<<<8, 512, 0, stream>>>(feats, topi, q_w1, q_b1, q_w2, q_b2, qmaxb);
    k_main<<<NB * SUBB, 256, 0, stream>>>(feats, w1t, w2t, q_b1, q_b2, qmaxb, s_ws, zp, Up);
    k_zred<<<8, 64, 0, stream>>>(zp, Zt);
    k_A<<<NB * NI * 2 / 256, 256, 0, stream>>>(s_ws, Zt, outA);
    k_B<<<8, 512, 0, stream>>>(Up, Zt, outB);
    k_C<<<8, 256, 0, stream>>>(outB, fcc_w, fcc_b, outC);
}

// Round 4
// 217.137 us; speedup vs baseline: 1.6745x; 1.6745x over previous
//
#include <hip/hip_runtime.h>
#include <hip/hip_bf16.h>

#define NB 4
#define NI 40000
#define DI 512
#define NH 128
#define TM 32
#define NTB 1250        // tiles per batch
#define SPB 64          // sub-blocks (persistent blocks) per batch; grid = 4*64 = 256

typedef __attribute__((ext_vector_type(8))) short bf16x8;
typedef __attribute__((ext_vector_type(4))) float f32x4;

#define GLOAD_LDS16(gp, lp)                                                     \
    __builtin_amdgcn_global_load_lds(                                           \
        (const __attribute__((address_space(1))) void*)(gp),                    \
        (__attribute__((address_space(3))) void*)(lp), 16, 0, 0)

#define ASM_VMCNT8() asm volatile("s_waitcnt vmcnt(8)" ::: "memory")
#define ASM_VMCNT0() asm volatile("s_waitcnt vmcnt(0)" ::: "memory")
#define ASM_LGKM0()  asm volatile("s_waitcnt lgkmcnt(0)" ::: "memory")
#define SCHED0()     __builtin_amdgcn_sched_barrier(0)
#define SBAR()       { asm volatile("" ::: "memory"); __builtin_amdgcn_s_barrier(); asm volatile("" ::: "memory"); }

__device__ __forceinline__ ushort f2b(float f) {
    union { float f; unsigned u; } x; x.f = f;
    unsigned r = x.u + 0x7FFFu + ((x.u >> 16) & 1u);
    return (ushort)(r >> 16);
}
__device__ __forceinline__ float tanh_fast(float x) {
    x = fminf(15.f, fmaxf(-15.f, x));
    float e = __expf(2.f * x);
    return (e - 1.f) / (e + 1.f);
}

// ---------------- weight transpose + bf16 convert ----------------
__global__ void k_wt(const float* __restrict__ w1, const float* __restrict__ w2,
                     ushort* __restrict__ w1t, ushort* __restrict__ w2t) {
    int idx = blockIdx.x * 256 + threadIdx.x;
    if (idx < 65536) {
        int j = idx >> 9, i = idx & 511;
        w1t[idx] = f2b(w1[i * 128 + j]);
    } else if (idx < 81920) {
        int r = idx - 65536;
        int j = r >> 7, k = r & 127;
        w2t[r] = f2b(w2[k * 128 + j]);
    }
}

// ---------------- argmax stage 1 ----------------
__global__ void k_am1(const float* __restrict__ c, float* __restrict__ pv, int* __restrict__ pi) {
    int blk = blockIdx.x;
    int bo = blk >> 4, ch = blk & 15;
    int b = bo >> 1, o = bo & 1;
    __shared__ float rv[256];
    __shared__ int   ri[256];
    int tid = threadIdx.x;
    float bv = -3.402823466e38f; int bi = 0x7fffffff;
    for (int n = ch * 2500 + tid; n < (ch + 1) * 2500; n += 256) {
        float v = c[((size_t)b * NI + n) * 2 + o];
        if (v > bv || (v == bv && n < bi)) { bv = v; bi = n; }
    }
    rv[tid] = bv; ri[tid] = bi;
    __syncthreads();
    for (int s = 128; s > 0; s >>= 1) {
        if (tid < s) {
            if (rv[tid + s] > rv[tid] || (rv[tid + s] == rv[tid] && ri[tid + s] < ri[tid])) {
                rv[tid] = rv[tid + s]; ri[tid] = ri[tid + s];
            }
        }
        __syncthreads();
    }
    if (tid == 0) { pv[blk] = rv[0]; pi[blk] = ri[0]; }
}

// ---------------- argmax stage 2 ----------------
__global__ void k_am2(const float* __restrict__ pv, const int* __restrict__ pi,
                      int* __restrict__ topidx) {
    int bo = blockIdx.x;
    if (threadIdx.x == 0) {
        float bv = -3.402823466e38f; int bi = 0x7fffffff;
        for (int ch = 0; ch < 16; ++ch) {
            float v = pv[bo * 16 + ch]; int idx = pi[bo * 16 + ch];
            if (v > bv || (v == bv && idx < bi)) { bv = v; bi = idx; }
        }
        topidx[bo] = bi;
    }
}

// ---------------- q_max MLP ----------------
__global__ void k_qmax(const float* __restrict__ feats, const int* __restrict__ topidx,
                       const float* __restrict__ w1, const float* __restrict__ b1,
                       const float* __restrict__ w2, const float* __restrict__ b2,
                       float* __restrict__ qmax) {
    int bo = blockIdx.x;
    int b = bo >> 1;
    __shared__ float xs[DI];
    __shared__ float hs[NH];
    int tid = threadIdx.x;               // 512
    const float* x = feats + ((size_t)b * NI + topidx[bo]) * DI;
    if (tid < DI) xs[tid] = x[tid];
    __syncthreads();
    int j = tid >> 2, part = tid & 3;
    float p = 0.f;
    for (int i = part * 128; i < part * 128 + 128; ++i)
        p += xs[i] * w1[i * NH + j];
    p += __shfl_xor(p, 1); p += __shfl_xor(p, 2);
    if (part == 0) { float h = p + b1[j]; hs[j] = h > 0.f ? h : 0.f; }
    __syncthreads();
    p = 0.f;
    for (int i = part * 32; i < part * 32 + 32; ++i)
        p += hs[i] * w2[i * NH + j];
    p += __shfl_xor(p, 1); p += __shfl_xor(p, 2);
    if (part == 0) qmax[bo * NH + j] = tanhf(p + b2[j]);
}

// ---------------- main fused kernel ----------------
// Persistent: 256 blocks (1/CU), 512 threads (8 waves), TM=32 rows/tile.
// X tiles: f32 via global_load_lds (width 16), double-buffered, source-side
// XOR swizzle (slot c4^(row&7)).  W1/W2 fragments live in VGPRs all block.
// Raw s_barrier + counted vmcnt(8): next tile's DMA stays in flight through
// the whole compute phase.
__global__ __launch_bounds__(512, 2)
void k_main(const float* __restrict__ feats,
            const ushort* __restrict__ w1t, const ushort* __restrict__ w2t,
            const float* __restrict__ b1, const float* __restrict__ b2,
            const float* __restrict__ qmax,
            float* __restrict__ ews, float* __restrict__ zp, float* __restrict__ Up) {
    __shared__ __align__(16) char x_lds[2 * 65536];   // 2 x (32 rows x 2048 B f32)
    __shared__ ushort h_lds[TM * NH];                 // 8 KB bf16, XOR-swizzled
    __shared__ float  sp_lds[4][TM][2];
    __shared__ float  e_lds[TM * 2];

    const int tid  = threadIdx.x;
    const int wave = tid >> 6;
    const int lane = tid & 63;
    const int sub  = blockIdx.x & (SPB - 1);
    const int b    = blockIdx.x >> 6;

    const int wm = wave >> 2;            // 0..1  (row half)
    const int wn = wave & 3;             // 0..3  (col quarter)
    const int lr = lane & 15;
    const int lk = (lane >> 4) * 8;
    const int l4 = (lane >> 4) * 4;

    // ---- per-thread constants / register-resident weights ----
    const int col0 = wn * 32 + lr;
    const int col1 = col0 + 16;
    const float rb1_0 = b1[col0], rb1_1 = b1[col1];
    const float rb2_0 = b2[col0], rb2_1 = b2[col1];
    const float qm00 = qmax[b * 256 + col0];
    const float qm01 = qmax[b * 256 + col1];
    const float qm10 = qmax[b * 256 + NH + col0];
    const float qm11 = qmax[b * 256 + NH + col1];

    bf16x8 W1f0[16], W1f1[16];
    {
        const ushort* wc0 = w1t + (size_t)col0 * DI + lk;
        const ushort* wc1 = w1t + (size_t)col1 * DI + lk;
#pragma unroll
        for (int ks = 0; ks < 16; ++ks) {
            W1f0[ks] = *(const bf16x8*)(wc0 + ks * 32);
            W1f1[ks] = *(const bf16x8*)(wc1 + ks * 32);
        }
    }
    bf16x8 W2f0[4], W2f1[4];
#pragma unroll
    for (int ks = 0; ks < 4; ++ks) {
        W2f0[ks] = *(const bf16x8*)&w2t[(size_t)col0 * NH + ks * 32 + lk];
        W2f1[ks] = *(const bf16x8*)&w2t[(size_t)col1 * NH + ks * 32 + lk];
    }

    const int cnt = (NTB - sub + SPB - 1) / SPB;     // 19 or 20 tiles
    const float* fb = feats + (size_t)b * NI * DI;

    // persistent accumulators
    float u0 = 0.f, u1 = 0.f, zacc = 0.f;

    // DMA issue: 8 x 16B per thread; source pre-swizzled so LDS slot (row,c4)
    // holds global chunk (row, c4^(row&7)).
    auto issue_tile = [&](int i, int bufsel) {
        const char* xg = (const char*)(fb + (size_t)(sub + SPB * i) * TM * DI);
        char* lbase = x_lds + bufsel * 65536 + wave * 1024;
#pragma unroll
        for (int q = 0; q < 8; ++q) {
            int idx = q * 512 + tid;
            int row = idx >> 7, c4 = idx & 127;
            const char* src = xg + row * 2048 + ((c4 ^ (row & 7)) << 4);
            GLOAD_LDS16(src, lbase + q * 8192);
        }
    };

    // ---- prologue ----
    issue_tile(0, 0);
    issue_tile(1, 1);
    ASM_VMCNT8();          // tile 0 landed (per wave)
    SCHED0();
    SBAR();                // all waves' slices landed -> buf0 ready

    int cur = 0;
    for (int i = 0; i < cnt; ++i) {
        const int n0 = (sub + SPB * i) * TM;
        const char* bufc = x_lds + cur * 65536;

        // ---- layer 1: X[32,512](f32 LDS) @ W1(regs) ----
        f32x4 acc0 = {}, acc1 = {};
        {
            const char* arow = bufc + (wm * 16 + lr) * 2048;
            const int rsw = lr & 7;
#pragma unroll
            for (int ks = 0; ks < 16; ++ks) {
                int c4a = ks * 8 + (lk >> 2);
                float4 xa = *(const float4*)(arow + ((c4a ^ rsw) << 4));
                float4 xb = *(const float4*)(arow + (((c4a + 1) ^ rsw) << 4));
                unsigned p0, p1, p2, p3;
                asm("v_cvt_pk_bf16_f32 %0, %1, %2" : "=v"(p0) : "v"(xa.x), "v"(xa.y));
                asm("v_cvt_pk_bf16_f32 %0, %1, %2" : "=v"(p1) : "v"(xa.z), "v"(xa.w));
                asm("v_cvt_pk_bf16_f32 %0, %1, %2" : "=v"(p2) : "v"(xb.x), "v"(xb.y));
                asm("v_cvt_pk_bf16_f32 %0, %1, %2" : "=v"(p3) : "v"(xb.z), "v"(xb.w));
                union { unsigned u[4]; bf16x8 v; } af;
                af.u[0] = p0; af.u[1] = p1; af.u[2] = p2; af.u[3] = p3;
                acc0 = __builtin_amdgcn_mfma_f32_16x16x32_bf16(af.v, W1f0[ks], acc0, 0, 0, 0);
                acc1 = __builtin_amdgcn_mfma_f32_16x16x32_bf16(af.v, W1f1[ks], acc1, 0, 0, 0);
            }
        }

        // ---- epilogue 1: bias + relu -> h_lds (bf16, swizzled) ----
#pragma unroll
        for (int r = 0; r < 4; ++r) {
            int row = wm * 16 + l4 + r;
            float v0 = acc0[r] + rb1_0;
            float v1 = acc1[r] + rb1_1;
            *(ushort*)((char*)h_lds + row * 256 + ((col0 * 2) ^ ((row & 7) << 4))) =
                f2b(v0 > 0.f ? v0 : 0.f);
            *(ushort*)((char*)h_lds + row * 256 + ((col1 * 2) ^ ((row & 7) << 4))) =
                f2b(v1 > 0.f ? v1 : 0.f);
        }
        ASM_LGKM0();
        SBAR();

        // ---- layer 2: H[32,128] @ W2(regs) ----
        f32x4 c20 = {}, c21 = {};
        {
            const char* hrow = (const char*)h_lds + (wm * 16 + lr) * 256;
            const int rsw2 = (lr & 7) << 4;
#pragma unroll
            for (int ks = 0; ks < 4; ++ks) {
                bf16x8 a = *(const bf16x8*)(hrow + ((ks * 64 + lk * 2) ^ rsw2));
                c20 = __builtin_amdgcn_mfma_f32_16x16x32_bf16(a, W2f0[ks], c20, 0, 0, 0);
                c21 = __builtin_amdgcn_mfma_f32_16x16x32_bf16(a, W2f1[ks], c21, 0, 0, 0);
            }
        }

        // ---- epilogue 2: tanh + dot(qmax), 16-lane reduce -> sp_lds ----
#pragma unroll
        for (int r = 0; r < 4; ++r) {
            float q0 = tanh_fast(c20[r] + rb2_0);
            float q1 = tanh_fast(c21[r] + rb2_1);
            float p0 = q0 * qm00 + q1 * qm01;
            float p1 = q0 * qm10 + q1 * qm11;
            p0 += __shfl_xor(p0, 1); p1 += __shfl_xor(p1, 1);
            p0 += __shfl_xor(p0, 2); p1 += __shfl_xor(p1, 2);
            p0 += __shfl_xor(p0, 4); p1 += __shfl_xor(p1, 4);
            p0 += __shfl_xor(p0, 8); p1 += __shfl_xor(p1, 8);
            if (lr == 0) {
                int row = wm * 16 + l4 + r;
                sp_lds[wn][row][0] = p0;
                sp_lds[wn][row][1] = p1;
            }
        }
        ASM_LGKM0();
        SBAR();

        // ---- s-finish (wave 0): e, global e-write, z partial ----
        if (tid < 64) {
            int row = tid >> 1, o = tid & 1;
            float s = (sp_lds[0][row][o] + sp_lds[1][row][o] +
                       sp_lds[2][row][o] + sp_lds[3][row][o]) * 0.005f;
            float e = __expf(s);
            e_lds[row * 2 + o] = e;
            ews[((size_t)(b * NI + n0 + row)) * 2 + o] = e;
            float z = e;
            z += __shfl_xor(z, 2);  z += __shfl_xor(z, 4);
            z += __shfl_xor(z, 8);  z += __shfl_xor(z, 16);
            z += __shfl_xor(z, 32);
            if (tid < 2) zacc += z;
        }
        ASM_LGKM0();
        SBAR();

        // ---- U phase: e-weighted f32 column sums (d = tid) ----
        {
            int slot = tid >> 2, lo4 = (tid & 3) * 4;
#pragma unroll 8
            for (int n = 0; n < TM; ++n) {
                float x = *(const float*)(bufc + n * 2048 + ((slot ^ (n & 7)) << 4) + lo4);
                u0 += e_lds[n * 2] * x;
                u1 += e_lds[n * 2 + 1] * x;
            }
        }
        ASM_LGKM0();       // all U reads of buf[cur] complete before DMA reuses it
        SBAR();

        // ---- prefetch tile i+2 into the buffer just freed ----
        if (i + 2 < cnt) {
            issue_tile(i + 2, cur);
            ASM_VMCNT8();  // tile i+1's 8 loads done; i+2's stay in flight
        } else {
            ASM_VMCNT0();  // drain tail
        }
        SCHED0();
        SBAR();            // buf[cur^1] ready for next iteration
        cur ^= 1;
    }

    // ---- block epilogue ----
    {
        size_t base = ((size_t)(b * SPB + sub) * 2) * DI;
        Up[base + tid] = u0;
        Up[base + DI + tid] = u1;
        if (tid < 2) zp[(b * SPB + sub) * 2 + tid] = zacc;
    }
}

// ---------------- Z reduce (64 partials per (b,o)) ----------------
__global__ void k_zred(const float* __restrict__ zp, float* __restrict__ Zt) {
    int bo = blockIdx.x; int b = bo >> 1, o = bo & 1;
    int tid = threadIdx.x;   // 64
    float z = zp[(b * SPB + tid) * 2 + o];
    z += __shfl_xor(z, 1);  z += __shfl_xor(z, 2);
    z += __shfl_xor(z, 4);  z += __shfl_xor(z, 8);
    z += __shfl_xor(z, 16); z += __shfl_xor(z, 32);
    if (tid == 0) Zt[bo] = z;
}

// ---------------- A output ----------------
__global__ void k_A(const float* __restrict__ ews, const float* __restrict__ Zt,
                    float* __restrict__ outA) {
    int idx = blockIdx.x * 256 + threadIdx.x;
    int b = idx / (NI * 2);
    int o = idx & 1;
    outA[idx] = ews[idx] / Zt[b * 2 + o];
}

// ---------------- B output (sum 64 partials) ----------------
__global__ void k_B(const float* __restrict__ Up, const float* __restrict__ Zt,
                    float* __restrict__ outB) {
    int bo = blockIdx.x; int d = threadIdx.x;   // 512
    int b = bo >> 1, o = bo & 1;
    float u = 0.f;
    for (int s2 = 0; s2 < SPB; ++s2)
        u += Up[(((size_t)(b * SPB + s2)) * 2 + o) * DI + d];
    outB[bo * DI + d] = u / Zt[bo];
}

// ---------------- C output ----------------
__global__ void k_C(const float* __restrict__ outB, const float* __restrict__ fcc_w,
                    const float* __restrict__ fcc_b, float* __restrict__ outC) {
    int bo = blockIdx.x; int b = bo >> 1, o = bo & 1;
    __shared__ float red[256];
    int tid = threadIdx.x;
    float acc = 0.f;
    for (int idx = tid; idx < 2 * DI; idx += 256) {
        int i = idx >> 9, d = idx & 511;
        acc += outB[(b * 2 + i) * DI + d] * fcc_w[o * (2 * DI) + i * DI + d];
    }
    red[tid] = acc; __syncthreads();
    for (int s = 128; s > 0; s >>= 1) {
        if (tid < s) red[tid] += red[tid + s];
        __syncthreads();
    }
    if (tid == 0) outC[bo] = red[0] + fcc_b[o];
}

extern "C" void kernel_launch(void* const* d_in, const int* in_sizes, int n_in,
                              void* d_out, int out_size, void* d_ws, size_t ws_size,
                              hipStream_t stream) {
    const float* feats = (const float*)d_in[0];
    const float* c     = (const float*)d_in[1];
    const float* q_w1  = (const float*)d_in[2];
    const float* q_b1  = (const float*)d_in[3];
    const float* q_w2  = (const float*)d_in[4];
    const float* q_b2  = (const float*)d_in[5];
    const float* fcc_w = (const float*)d_in[6];
    const float* fcc_b = (const float*)d_in[7];
    float* out = (float*)d_out;

    // workspace layout (bytes)
    char* w = (char*)d_ws;
    ushort* w1t  = (ushort*)(w);                 // 131072
    ushort* w2t  = (ushort*)(w + 131072);        //  32768 -> 163840
    float* qmaxb = (float*)(w + 163840);         //   4096 -> 167936
    int*   topi  = (int*)(w + 167936);           //     32 -> 167968
    float* Zt    = (float*)(w + 167968);         //     32 -> 168000
    float* pv    = (float*)(w + 168000);         //    512 -> 168512
    int*   pi    = (int*)(w + 168512);           //    512 -> 169024
    float* ews   = (float*)(w + 169024);         // 1280000 -> 1449024
    float* zp    = (float*)(w + 1449024);        //   2048 -> 1451072
    float* Up    = (float*)(w + 1451072);        // 1048576 -> 2499648

    float* outC = out;
    float* outA = out + 8;
    float* outB = out + 8 + NB * NI * 2;

    k_wt<<<320, 256, 0, stream>>>(q_w1, q_w2, w1t, w2t);
    k_am1<<<128, 256, 0, stream>>>(c, pv, pi);
    k_am2<<<8, 64, 0, stream>>>(pv, pi, topi);
    k_qmax<<<8, 512, 0, stream>>>(feats, topi, q_w1, q_b1, q_w2, q_b2, qmaxb);
    k_main<<<NB * SPB, 512, 0, stream>>>(feats, w1t, w2t, q_b1, q_b2, qmaxb, ews, zp, Up);
    k_zred<<<8, 64, 0, stream>>>(zp, Zt);
    k_A<<<NB * NI * 2 / 256, 256, 0, stream>>>(ews, Zt, outA);
    k_B<<<8, 512, 0, stream>>>(Up, Zt, outB);
    k_C<<<8, 256, 0, stream>>>(outB, fcc_w, fcc_b, outC);
}